// Round 15
// baseline (460.430 us; speedup 1.0000x reference)
//
#include <hip/hip_runtime.h>
#include <hip/hip_bf16.h>
#include <stdint.h>

// ---------------------------------------------------------------------------
// EfficientDAGNN: y_k = relu(concat(prev) @ (W_k*M_k)^T + b_k), 4 layers.
// R15 = R13 (258us best: 2-stage LDS DMA pipeline, pre-swizzled
// global_load_lds, counted vmcnt, SPLITK=8) + phaseB fused as last-block
// epilogue (threadfence + per-chunk atomic ticket), 9 launches -> 5.
// R7's fusion failure (VGPR 128->100 pipeline collapse) shouldn't recur:
// K-loop state now lives in LDS, launch_bounds(256,1) caps VGPR at 256.
// R14's 4-stage pipeline regressed (latency depth exhausted) - reverted.
// Split-bf16 (hi+lo) 3-term MFMA, fp32 split-K partials.
// Activation plane: [64][16384] bf16 hi+lo, cols: [x | y1 | y2 | y3].
// ---------------------------------------------------------------------------

typedef __attribute__((ext_vector_type(8))) short  s8v;    // 8 bf16 (MFMA frag)
typedef __attribute__((ext_vector_type(4))) float  f4v;
typedef __attribute__((ext_vector_type(4))) unsigned short us4v;

#define LDA 16384              // activation plane leading dim (bf16 elems)
#define MFMA16 __builtin_amdgcn_mfma_f32_16x16x32_bf16

typedef __attribute__((address_space(3))) void       lds_void;
typedef const __attribute__((address_space(1))) void g_void;

// fp32 -> bf16 RTNE (no NaNs in this problem)
__device__ __forceinline__ short f2bf(float f) {
  unsigned int u = __builtin_bit_cast(unsigned int, f);
  u += 0x7fffu + ((u >> 16) & 1u);
  return (short)(u >> 16);
}
__device__ __forceinline__ float bf2f(short s) {
  unsigned int u = ((unsigned int)(unsigned short)s) << 16;
  return __builtin_bit_cast(float, u);
}

// ---------------------------------------------------------------------------
// splitx: x (fp32 [64][4096]) -> xh/xl bf16 into cols [0,4096) of the plane.
// Also zeroes the 4x32 per-layer chunk counters.
// ---------------------------------------------------------------------------
__global__ void dag_splitx(const float* __restrict__ x,
                           ushort* __restrict__ xh, ushort* __restrict__ xl,
                           int* __restrict__ counters) {
  int idx = blockIdx.x * blockDim.x + threadIdx.x;   // 65536 float4 units
  if (blockIdx.x == 0 && threadIdx.x < 128) counters[threadIdx.x] = 0;
  int m = idx >> 10;
  int n = (idx & 1023) << 2;
  f4v v = *(const f4v*)(x + (size_t)m * 4096 + n);
  us4v h, l;
#pragma unroll
  for (int j = 0; j < 4; ++j) {
    short hh = f2bf(v[j]);
    h[j] = (unsigned short)hh;
    l[j] = (unsigned short)f2bf(v[j] - bf2f(hh));
  }
  *(us4v*)(xh + (size_t)m * LDA + n) = h;
  *(us4v*)(xl + (size_t)m * LDA + n) = l;
}

// ---------------------------------------------------------------------------
// Fused layer: R13's phaseA (2-stage LDS DMA pipeline, per-wave-private LDS,
// no barriers in the K-loop) + last-block-per-chunk phaseB epilogue.
// grid = (32, SPLITK), block = 256 (4 waves), dynamic LDS 128KB.
// ---------------------------------------------------------------------------
struct RA { s8v ah0, ah1, ah2, ah3, al0, al1, al2, al3; };

template <int NSUPER>
__global__ __launch_bounds__(256, 1) void dag_layer(
    const ushort* __restrict__ Ah,   // already offset to layer's col start
    const ushort* __restrict__ Al,
    const float*  __restrict__ W,    // [4096][K] row-major
    const float*  __restrict__ Mm,   // [4096][K]
    float*        __restrict__ partial,  // [SPLITK][64][4096]
    int K, int splitk,
    int* __restrict__ cnt,           // 32 per-chunk tickets for this layer
    const float* __restrict__ bias,
    ushort* __restrict__ yh,         // next-layer plane cols (null on last)
    ushort* __restrict__ yl,
    float*  __restrict__ yf) {       // d_out on last layer (else null)
  extern __shared__ float smem[];    // 128KB: 4 waves x 2 stages x (W|M 8KB)
  const int tid  = threadIdx.x;
  const int wave = tid >> 6, lane = tid & 63;
  const int l15  = lane & 15, blk = lane >> 4;
  const int n0   = blockIdx.x * 128 + wave * 32;   // wave's output-col base
  const int klen = NSUPER * 64;
  const int kbeg = blockIdx.y * klen;

  float* base = smem + wave * 8192;  // 32KB per wave
  float* WL0 = base;                 // stage0 W [32][64]
  float* ML0 = base + 2048;          // stage0 M
  float* WL1 = base + 4096;          // stage1 W
  float* ML1 = base + 6144;          // stage1 M

  const int srow = lane >> 4;        // 0..3: row within 4-row DMA group
  const int sc   = lane & 15;        // 16B chunk index within 256B row

  // A: lane reads row (mt*16+l15), 8 consecutive k (16B of bf16)
  const ushort* ap  = Ah + (size_t)l15 * LDA + kbeg + blk * 8;
  const ushort* alp = Al + (size_t)l15 * LDA + kbeg + blk * 8;

  f4v acc[4][2];
#pragma unroll
  for (int i = 0; i < 4; ++i) {
    acc[i][0] = (f4v){0.f, 0.f, 0.f, 0.f};
    acc[i][1] = (f4v){0.f, 0.f, 0.f, 0.f};
  }
  RA a0, a1;

  // DMA stage s. Pre-swizzled global chunk (sc ^ row&15), linear LDS dest:
  // LDS[row][c] then holds global chunk c ^ (row&15).
  auto GLDS = [&](int s, float* WB, float* MB) {
#pragma unroll
    for (int j = 0; j < 8; ++j) {
      int row4 = 4 * j + srow;
      int gc   = sc ^ (row4 & 15);
      const float* ws = W  + (size_t)(n0 + row4) * K + kbeg + s * 64 + gc * 4;
      const float* ms = Mm + (size_t)(n0 + row4) * K + kbeg + s * 64 + gc * 4;
      __builtin_amdgcn_global_load_lds((g_void*)ws, (lds_void*)(WB + j * 256),
                                       16, 0, 0);
      __builtin_amdgcn_global_load_lds((g_void*)ms, (lds_void*)(MB + j * 256),
                                       16, 0, 0);
    }
  };
  auto LOADA = [&](RA& r, int ko) {
    r.ah0 = *(const s8v*)(ap  + ko);
    r.ah1 = *(const s8v*)(ap  + (size_t)16 * LDA + ko);
    r.ah2 = *(const s8v*)(ap  + (size_t)32 * LDA + ko);
    r.ah3 = *(const s8v*)(ap  + (size_t)48 * LDA + ko);
    r.al0 = *(const s8v*)(alp + ko);
    r.al1 = *(const s8v*)(alp + (size_t)16 * LDA + ko);
    r.al2 = *(const s8v*)(alp + (size_t)32 * LDA + ko);
    r.al3 = *(const s8v*)(alp + (size_t)48 * LDA + ko);
  };

  // One 32-k MFMA step: swizzled LDS fragment reads, repack, 24 MFMA.
  auto KSTEP = [&](int kstep, RA& ra, float* WL, float* ML) {
    const int cc = kstep * 8 + blk * 2;
    const int c0 = cc ^ l15, c1 = (cc + 1) ^ l15;
    const float* wr0 = WL + l15 * 64;
    const float* wr1 = WL + (l15 + 16) * 64;
    const float* mr0 = ML + l15 * 64;
    const float* mr1 = ML + (l15 + 16) * 64;
    f4v w0a = *(const f4v*)(wr0 + c0 * 4), w0b = *(const f4v*)(wr0 + c1 * 4);
    f4v w1a = *(const f4v*)(wr1 + c0 * 4), w1b = *(const f4v*)(wr1 + c1 * 4);
    f4v m0a = *(const f4v*)(mr0 + c0 * 4), m0b = *(const f4v*)(mr0 + c1 * 4);
    f4v m1a = *(const f4v*)(mr1 + c0 * 4), m1b = *(const f4v*)(mr1 + c1 * 4);

    s8v wh0, wl0, wh1, wl1;
#pragma unroll
    for (int j = 0; j < 4; ++j) {
      { float ww = w0a[j] * m0a[j]; short h = f2bf(ww);
        wh0[j]     = h; wl0[j]     = f2bf(ww - bf2f(h)); }
      { float ww = w0b[j] * m0b[j]; short h = f2bf(ww);
        wh0[j + 4] = h; wl0[j + 4] = f2bf(ww - bf2f(h)); }
      { float ww = w1a[j] * m1a[j]; short h = f2bf(ww);
        wh1[j]     = h; wl1[j]     = f2bf(ww - bf2f(h)); }
      { float ww = w1b[j] * m1b[j]; short h = f2bf(ww);
        wh1[j + 4] = h; wl1[j + 4] = f2bf(ww - bf2f(h)); }
    }
    acc[0][0] = MFMA16(ra.ah0, wh0, acc[0][0], 0, 0, 0);
    acc[0][0] = MFMA16(ra.al0, wh0, acc[0][0], 0, 0, 0);
    acc[0][0] = MFMA16(ra.ah0, wl0, acc[0][0], 0, 0, 0);
    acc[1][0] = MFMA16(ra.ah1, wh0, acc[1][0], 0, 0, 0);
    acc[1][0] = MFMA16(ra.al1, wh0, acc[1][0], 0, 0, 0);
    acc[1][0] = MFMA16(ra.ah1, wl0, acc[1][0], 0, 0, 0);
    acc[2][0] = MFMA16(ra.ah2, wh0, acc[2][0], 0, 0, 0);
    acc[2][0] = MFMA16(ra.al2, wh0, acc[2][0], 0, 0, 0);
    acc[2][0] = MFMA16(ra.ah2, wl0, acc[2][0], 0, 0, 0);
    acc[3][0] = MFMA16(ra.ah3, wh0, acc[3][0], 0, 0, 0);
    acc[3][0] = MFMA16(ra.al3, wh0, acc[3][0], 0, 0, 0);
    acc[3][0] = MFMA16(ra.ah3, wl0, acc[3][0], 0, 0, 0);
    acc[0][1] = MFMA16(ra.ah0, wh1, acc[0][1], 0, 0, 0);
    acc[0][1] = MFMA16(ra.al0, wh1, acc[0][1], 0, 0, 0);
    acc[0][1] = MFMA16(ra.ah0, wl1, acc[0][1], 0, 0, 0);
    acc[1][1] = MFMA16(ra.ah1, wh1, acc[1][1], 0, 0, 0);
    acc[1][1] = MFMA16(ra.al1, wh1, acc[1][1], 0, 0, 0);
    acc[1][1] = MFMA16(ra.ah1, wl1, acc[1][1], 0, 0, 0);
    acc[2][1] = MFMA16(ra.ah2, wh1, acc[2][1], 0, 0, 0);
    acc[2][1] = MFMA16(ra.al2, wh1, acc[2][1], 0, 0, 0);
    acc[2][1] = MFMA16(ra.ah2, wl1, acc[2][1], 0, 0, 0);
    acc[3][1] = MFMA16(ra.ah3, wh1, acc[3][1], 0, 0, 0);
    acc[3][1] = MFMA16(ra.al3, wh1, acc[3][1], 0, 0, 0);
    acc[3][1] = MFMA16(ra.ah3, wl1, acc[3][1], 0, 0, 0);
  };

  // prologue: DMA stage 0; A fragments; drain DMA (keep A-loads in flight)
  GLDS(0, WL0, ML0);
  LOADA(a0, 0);
  LOADA(a1, 32);
  asm volatile("s_waitcnt vmcnt(16)" ::: "memory");
  __builtin_amdgcn_sched_barrier(0);

#pragma unroll
  for (int s = 0; s < NSUPER; ++s) {
    float* curW = (s & 1) ? WL1 : WL0;
    float* curM = (s & 1) ? ML1 : ML0;
    float* nxtW = (s & 1) ? WL0 : WL1;
    float* nxtM = (s & 1) ? ML0 : ML1;
    if (s + 1 < NSUPER) GLDS(s + 1, nxtW, nxtM);   // DMA next stage early
    KSTEP(0, a0, curW, curM);
    if (s + 1 < NSUPER) LOADA(a0, (s + 1) * 64);
    KSTEP(1, a1, curW, curM);
    if (s + 1 < NSUPER) LOADA(a1, (s + 1) * 64 + 32);
    if (s + 1 < NSUPER) {
      asm volatile("s_waitcnt vmcnt(16)" ::: "memory");
      __builtin_amdgcn_sched_barrier(0);
    }
  }

  // write fp32 partials
  float* pout = partial + (size_t)blockIdx.y * (64 * 4096);
#pragma unroll
  for (int mt = 0; mt < 4; ++mt)
#pragma unroll
    for (int nt = 0; nt < 2; ++nt) {
      int n = n0 + nt * 16 + l15;
#pragma unroll
      for (int rr = 0; rr < 4; ++rr) {
        int m = mt * 16 + blk * 4 + rr;
        pout[(size_t)m * 4096 + n] = acc[mt][nt][rr];
      }
    }

  // ---- fused phase B: last block for this n-chunk reduces + finishes ----
  __shared__ int is_last;
  __threadfence();                 // release partial writes (device scope)
  __syncthreads();
  if (tid == 0) {
    int ticket = atomicAdd(&cnt[blockIdx.x], 1);
    is_last = (ticket == splitk - 1) ? 1 : 0;
  }
  __syncthreads();
  if (is_last) {
    __threadfence();               // acquire: see all producers' partials
    const int nbase = blockIdx.x * 128;
#pragma unroll
    for (int i = 0; i < 8; ++i) {
      int idx = tid + (i << 8);    // 2048 f4v units: 64 m x 32 col-quads
      int m   = idx >> 5;
      int n   = nbase + ((idx & 31) << 2);
      const float* p = partial + (size_t)m * 4096 + n;
      f4v s = (f4v){0.f, 0.f, 0.f, 0.f};
      for (int sp = 0; sp < splitk; ++sp)
        s += *(const f4v*)(p + (size_t)sp * (64 * 4096));
      const f4v bv = *(const f4v*)(bias + n);
      f4v y;
#pragma unroll
      for (int j = 0; j < 4; ++j) y[j] = fmaxf(s[j] + bv[j], 0.f);
      if (yf) {
        *(f4v*)(yf + (size_t)m * 4096 + n) = y;
      } else {
        us4v h, l;
#pragma unroll
        for (int j = 0; j < 4; ++j) {
          short hh = f2bf(y[j]);
          h[j] = (unsigned short)hh;
          l[j] = (unsigned short)f2bf(y[j] - bf2f(hh));
        }
        *(us4v*)(yh + (size_t)m * LDA + n) = h;
        *(us4v*)(yl + (size_t)m * LDA + n) = l;
      }
    }
  }
}

// ---------------------------------------------------------------------------
extern "C" void kernel_launch(void* const* d_in, const int* in_sizes, int n_in,
                              void* d_out, int out_size, void* d_ws, size_t ws_size,
                              hipStream_t stream) {
  (void)in_sizes; (void)n_in; (void)out_size;
  const float* x = (const float*)d_in[0];
  struct L { const float *W, *b, *M; int K, incol, outcol; };
  L Ls[4] = {
      {(const float*)d_in[1],  (const float*)d_in[2],  (const float*)d_in[3],  4096, 0,    4096},
      {(const float*)d_in[4],  (const float*)d_in[5],  (const float*)d_in[6],  8192, 0,    8192},
      {(const float*)d_in[7],  (const float*)d_in[8],  (const float*)d_in[9],  8192, 4096, 12288},
      {(const float*)d_in[10], (const float*)d_in[11], (const float*)d_in[12], 8192, 8192, 16384},
  };
  float* out = (float*)d_out;

  // workspace: Ah(2MB) | Al(2MB) | partial(SPLITK MB) | counters(128 ints)
  char* ws = (char*)d_ws;
  ushort* Ah = (ushort*)ws;
  ushort* Al = (ushort*)(ws + (size_t)64 * LDA * 2);
  float* partial = (float*)(ws + (size_t)2 * 64 * LDA * 2);
  int SPLITK = 8;    // grid (32,8) = 256 blocks = exactly 1 resident block/CU
  while (SPLITK > 4 &&
         ws_size < (size_t)4 * 1024 * 1024 + (size_t)SPLITK * 1024 * 1024 + 512)
    SPLITK >>= 1;
  int* counters = (int*)(ws + (size_t)4 * 1024 * 1024 +
                         (size_t)SPLITK * 1024 * 1024);

  const int smem = 131072;   // 128KB dynamic LDS (> 64KB default: opt in)
  hipFuncSetAttribute((const void*)dag_layer<8>,
                      hipFuncAttributeMaxDynamicSharedMemorySize, smem);
  hipFuncSetAttribute((const void*)dag_layer<16>,
                      hipFuncAttributeMaxDynamicSharedMemorySize, smem);
  hipFuncSetAttribute((const void*)dag_layer<32>,
                      hipFuncAttributeMaxDynamicSharedMemorySize, smem);

  dag_splitx<<<256, 256, 0, stream>>>(x, Ah, Al, counters);

  for (int k = 0; k < 4; ++k) {
    bool last = (k == 3);
    dim3 grid(32, SPLITK);
    const ushort* Ahp = Ah + Ls[k].incol;
    const ushort* Alp = Al + Ls[k].incol;
    ushort* yh = last ? (ushort*)nullptr : Ah + Ls[k].outcol;
    ushort* yl = last ? (ushort*)nullptr : Al + Ls[k].outcol;
    float*  yf = last ? out : (float*)nullptr;
    int nsuper = (Ls[k].K / SPLITK) / 64;
    switch (nsuper) {
      case 8:
        dag_layer<8><<<grid, 256, smem, stream>>>(
            Ahp, Alp, Ls[k].W, Ls[k].M, partial, Ls[k].K, SPLITK,
            counters + k * 32, Ls[k].b, yh, yl, yf);
        break;
      case 16:
        dag_layer<16><<<grid, 256, smem, stream>>>(
            Ahp, Alp, Ls[k].W, Ls[k].M, partial, Ls[k].K, SPLITK,
            counters + k * 32, Ls[k].b, yh, yl, yf);
        break;
      default:
        dag_layer<32><<<grid, 256, smem, stream>>>(
            Ahp, Alp, Ls[k].W, Ls[k].M, partial, Ls[k].K, SPLITK,
            counters + k * 32, Ls[k].b, yh, yl, yf);
        break;
    }
  }
}

// Round 16
// 305.049 us; speedup vs baseline: 1.5094x; 1.5094x over previous
//
#include <hip/hip_runtime.h>
#include <hip/hip_bf16.h>
#include <stdint.h>

// ---------------------------------------------------------------------------
// EfficientDAGNN: y_k = relu(concat(prev) @ (W_k*M_k)^T + b_k), 4 layers.
// R16 = R13 (258us best) with 8-wave phaseA blocks (512 thr, wave tile
// 64m x 16n, per-wave 2-stage [16r][64k] DMA pipeline, 128KB LDS, 1
// block/CU): 2 waves/SIMD so vmcnt stalls overlap with the co-wave's
// compute (R13 had 1 wave/SIMD - every DMA-drain stall idled the SIMD).
// R15's fused epilogue collapsed codegen AGAIN (VGPR 124, 1TB/s) - fusion
// permanently abandoned; separate phaseB kept.
// Split-bf16 (hi+lo) 3-term MFMA, fp32 split-K partials, SPLITK=8.
// Activation plane: [64][16384] bf16 hi+lo, cols: [x | y1 | y2 | y3].
// ---------------------------------------------------------------------------

typedef __attribute__((ext_vector_type(8))) short  s8v;    // 8 bf16 (MFMA frag)
typedef __attribute__((ext_vector_type(4))) float  f4v;
typedef __attribute__((ext_vector_type(2))) float  f2v;
typedef __attribute__((ext_vector_type(4))) unsigned short us4v;
typedef __attribute__((ext_vector_type(2))) unsigned short us2v;

#define LDA 16384              // activation plane leading dim (bf16 elems)
#define MFMA16 __builtin_amdgcn_mfma_f32_16x16x32_bf16

typedef __attribute__((address_space(3))) void       lds_void;
typedef const __attribute__((address_space(1))) void g_void;

// fp32 -> bf16 RTNE (no NaNs in this problem)
__device__ __forceinline__ short f2bf(float f) {
  unsigned int u = __builtin_bit_cast(unsigned int, f);
  u += 0x7fffu + ((u >> 16) & 1u);
  return (short)(u >> 16);
}
__device__ __forceinline__ float bf2f(short s) {
  unsigned int u = ((unsigned int)(unsigned short)s) << 16;
  return __builtin_bit_cast(float, u);
}

// ---------------------------------------------------------------------------
// splitx: x (fp32 [64][4096]) -> xh/xl bf16 into cols [0,4096) of the plane
// ---------------------------------------------------------------------------
__global__ void dag_splitx(const float* __restrict__ x,
                           ushort* __restrict__ xh, ushort* __restrict__ xl) {
  int idx = blockIdx.x * blockDim.x + threadIdx.x;   // 65536 float4 units
  int m = idx >> 10;
  int n = (idx & 1023) << 2;
  f4v v = *(const f4v*)(x + (size_t)m * 4096 + n);
  us4v h, l;
#pragma unroll
  for (int j = 0; j < 4; ++j) {
    short hh = f2bf(v[j]);
    h[j] = (unsigned short)hh;
    l[j] = (unsigned short)f2bf(v[j] - bf2f(hh));
  }
  *(us4v*)(xh + (size_t)m * LDA + n) = h;
  *(us4v*)(xl + (size_t)m * LDA + n) = l;
}

// ---------------------------------------------------------------------------
// Phase A: partial[split][64][4096] = A[64][klen] @ (W*M)^T[klen][4096]
// 8 waves/block (512 thr), wave tile 64m x 16n. Per super-iter a wave DMAs
// [16 rows][64 k] of W and M (8 x global_load_lds, pre-swizzled source) into
// its spare stage while 2 KSTEPs consume the current stage. 2 waves/SIMD.
// Per-wave-private LDS: no barriers. grid = (32, SPLITK), dyn LDS 128KB.
// ---------------------------------------------------------------------------
struct RA { s8v ah0, ah1, ah2, ah3, al0, al1, al2, al3; };

template <int NSUPER>
__global__ __launch_bounds__(512, 1) void dag_gemm_phaseA(
    const ushort* __restrict__ Ah,   // already offset to layer's col start
    const ushort* __restrict__ Al,
    const float*  __restrict__ W,    // [4096][K] row-major
    const float*  __restrict__ Mm,   // [4096][K]
    float*        __restrict__ partial,  // [SPLITK][64][4096]
    int K) {
  extern __shared__ float smem[];    // 128KB: 8 waves x 2 stages x (W|M 4KB)
  const int tid  = threadIdx.x;
  const int wave = tid >> 6, lane = tid & 63;
  const int l15  = lane & 15, blk = lane >> 4;
  const int n0   = blockIdx.x * 128 + wave * 16;   // wave's output-col base
  const int klen = NSUPER * 64;
  const int kbeg = blockIdx.y * klen;

  float* base = smem + wave * 4096;  // 16KB per wave
  float* WL0 = base;                 // stage0 W [16][64]
  float* ML0 = base + 1024;          // stage0 M
  float* WL1 = base + 2048;          // stage1 W
  float* ML1 = base + 3072;          // stage1 M

  const int srow = lane >> 4;        // 0..3: row within 4-row DMA group
  const int sc   = lane & 15;        // 16B chunk index within 256B row

  // A: lane reads row (mt*16+l15), 8 consecutive k (16B of bf16)
  const ushort* ap  = Ah + (size_t)l15 * LDA + kbeg + blk * 8;
  const ushort* alp = Al + (size_t)l15 * LDA + kbeg + blk * 8;

  f4v acc[4];
#pragma unroll
  for (int i = 0; i < 4; ++i) acc[i] = (f4v){0.f, 0.f, 0.f, 0.f};
  RA a0, a1;

  // DMA stage s: 16 rows x 64 k of W and M (4 instrs each, 1KB per instr).
  // Pre-swizzled source chunk gc = sc ^ row (row 0..15); linear LDS dest:
  // LDS[row][c] then holds global chunk c ^ row.
  auto GLDS = [&](int s, float* WB, float* MB) {
#pragma unroll
    for (int j = 0; j < 4; ++j) {
      int row4 = 4 * j + srow;           // 0..15
      int gc   = sc ^ row4;
      const float* ws = W  + (size_t)(n0 + row4) * K + kbeg + s * 64 + gc * 4;
      const float* ms = Mm + (size_t)(n0 + row4) * K + kbeg + s * 64 + gc * 4;
      __builtin_amdgcn_global_load_lds((g_void*)ws, (lds_void*)(WB + j * 256),
                                       16, 0, 0);
      __builtin_amdgcn_global_load_lds((g_void*)ms, (lds_void*)(MB + j * 256),
                                       16, 0, 0);
    }
  };
  auto LOADA = [&](RA& r, int ko) {
    r.ah0 = *(const s8v*)(ap  + ko);
    r.ah1 = *(const s8v*)(ap  + (size_t)16 * LDA + ko);
    r.ah2 = *(const s8v*)(ap  + (size_t)32 * LDA + ko);
    r.ah3 = *(const s8v*)(ap  + (size_t)48 * LDA + ko);
    r.al0 = *(const s8v*)(alp + ko);
    r.al1 = *(const s8v*)(alp + (size_t)16 * LDA + ko);
    r.al2 = *(const s8v*)(alp + (size_t)32 * LDA + ko);
    r.al3 = *(const s8v*)(alp + (size_t)48 * LDA + ko);
  };

  // One 32-k MFMA step: swizzled LDS fragment reads (16 rows), repack,
  // 12 MFMAs (3-term split-bf16 over 4 m-tiles).
  auto KSTEP = [&](int kstep, RA& ra, float* WL, float* ML) {
    const int cc = kstep * 8 + blk * 2;
    const int c0 = cc ^ l15, c1 = (cc + 1) ^ l15;
    const float* wr0 = WL + l15 * 64;
    const float* mr0 = ML + l15 * 64;
    f4v w0a = *(const f4v*)(wr0 + c0 * 4), w0b = *(const f4v*)(wr0 + c1 * 4);
    f4v m0a = *(const f4v*)(mr0 + c0 * 4), m0b = *(const f4v*)(mr0 + c1 * 4);

    s8v wh0, wl0;
#pragma unroll
    for (int j = 0; j < 4; ++j) {
      { float ww = w0a[j] * m0a[j]; short h = f2bf(ww);
        wh0[j]     = h; wl0[j]     = f2bf(ww - bf2f(h)); }
      { float ww = w0b[j] * m0b[j]; short h = f2bf(ww);
        wh0[j + 4] = h; wl0[j + 4] = f2bf(ww - bf2f(h)); }
    }
    // 3-term split product: ah*wh + al*wh + ah*wl  (al*wl ~ 2^-18, dropped)
    acc[0] = MFMA16(ra.ah0, wh0, acc[0], 0, 0, 0);
    acc[0] = MFMA16(ra.al0, wh0, acc[0], 0, 0, 0);
    acc[0] = MFMA16(ra.ah0, wl0, acc[0], 0, 0, 0);
    acc[1] = MFMA16(ra.ah1, wh0, acc[1], 0, 0, 0);
    acc[1] = MFMA16(ra.al1, wh0, acc[1], 0, 0, 0);
    acc[1] = MFMA16(ra.ah1, wl0, acc[1], 0, 0, 0);
    acc[2] = MFMA16(ra.ah2, wh0, acc[2], 0, 0, 0);
    acc[2] = MFMA16(ra.al2, wh0, acc[2], 0, 0, 0);
    acc[2] = MFMA16(ra.ah2, wl0, acc[2], 0, 0, 0);
    acc[3] = MFMA16(ra.ah3, wh0, acc[3], 0, 0, 0);
    acc[3] = MFMA16(ra.al3, wh0, acc[3], 0, 0, 0);
    acc[3] = MFMA16(ra.ah3, wl0, acc[3], 0, 0, 0);
  };

  // prologue: DMA stage 0; A fragments; drain the 8 DMA loads
  // (vmcnt(16) leaves the 16 A-loads in flight).
  GLDS(0, WL0, ML0);
  LOADA(a0, 0);
  LOADA(a1, 32);
  asm volatile("s_waitcnt vmcnt(16)" ::: "memory");
  __builtin_amdgcn_sched_barrier(0);

#pragma unroll
  for (int s = 0; s < NSUPER; ++s) {
    float* curW = (s & 1) ? WL1 : WL0;
    float* curM = (s & 1) ? ML1 : ML0;
    float* nxtW = (s & 1) ? WL0 : WL1;
    float* nxtM = (s & 1) ? ML0 : ML1;
    if (s + 1 < NSUPER) GLDS(s + 1, nxtW, nxtM);   // DMA next stage early
    KSTEP(0, a0, curW, curM);
    if (s + 1 < NSUPER) LOADA(a0, (s + 1) * 64);
    KSTEP(1, a1, curW, curM);
    if (s + 1 < NSUPER) LOADA(a1, (s + 1) * 64 + 32);
    if (s + 1 < NSUPER) {
      // drain this iter's 8 DMA loads; keep the 16 fresh A-loads in flight
      asm volatile("s_waitcnt vmcnt(16)" ::: "memory");
      __builtin_amdgcn_sched_barrier(0);
    }
  }

  // write fp32 partials: C row m = mt*16 + blk*4 + r, col n = n0 + l15
  float* pout = partial + (size_t)blockIdx.y * (64 * 4096);
#pragma unroll
  for (int mt = 0; mt < 4; ++mt) {
    int n = n0 + l15;
#pragma unroll
    for (int rr = 0; rr < 4; ++rr) {
      int m = mt * 16 + blk * 4 + rr;
      pout[(size_t)m * 4096 + n] = acc[mt][rr];
    }
  }
}

// ---------------------------------------------------------------------------
// Phase B: reduce split-K partials + bias + relu; re-split to bf16 hi/lo
// (next layer's input); layer 4 writes fp32 d_out instead.
// ---------------------------------------------------------------------------
__global__ void dag_phaseB(const float* __restrict__ partial, int splitk,
                           const float* __restrict__ bias,
                           ushort* __restrict__ yh, ushort* __restrict__ yl,
                           float* __restrict__ yf) {
  int idx = blockIdx.x * blockDim.x + threadIdx.x;   // 131072 f2v units
  int m = idx >> 11;
  int n = (idx & 2047) << 1;
  const float* p = partial + (size_t)m * 4096 + n;
  float s0 = 0.f, s1 = 0.f;
#pragma unroll 4
  for (int sp = 0; sp < splitk; ++sp) {
    f2v v = *(const f2v*)(p + (size_t)sp * (64 * 4096));
    s0 += v[0]; s1 += v[1];
  }
  const f2v bv = *(const f2v*)(bias + n);
  s0 = fmaxf(s0 + bv[0], 0.f);
  s1 = fmaxf(s1 + bv[1], 0.f);
  if (yf) {
    *(f2v*)(yf + (size_t)m * 4096 + n) = (f2v){s0, s1};
  } else {
    us2v h, l;
    short h0 = f2bf(s0); h[0] = (unsigned short)h0;
    l[0] = (unsigned short)f2bf(s0 - bf2f(h0));
    short h1 = f2bf(s1); h[1] = (unsigned short)h1;
    l[1] = (unsigned short)f2bf(s1 - bf2f(h1));
    *(us2v*)(yh + (size_t)m * LDA + n) = h;
    *(us2v*)(yl + (size_t)m * LDA + n) = l;
  }
}

// ---------------------------------------------------------------------------
extern "C" void kernel_launch(void* const* d_in, const int* in_sizes, int n_in,
                              void* d_out, int out_size, void* d_ws, size_t ws_size,
                              hipStream_t stream) {
  (void)in_sizes; (void)n_in; (void)out_size;
  const float* x = (const float*)d_in[0];
  struct L { const float *W, *b, *M; int K, incol, outcol; };
  L Ls[4] = {
      {(const float*)d_in[1],  (const float*)d_in[2],  (const float*)d_in[3],  4096, 0,    4096},
      {(const float*)d_in[4],  (const float*)d_in[5],  (const float*)d_in[6],  8192, 0,    8192},
      {(const float*)d_in[7],  (const float*)d_in[8],  (const float*)d_in[9],  8192, 4096, 12288},
      {(const float*)d_in[10], (const float*)d_in[11], (const float*)d_in[12], 8192, 8192, 16384},
  };
  float* out = (float*)d_out;

  // workspace: Ah(2MB) | Al(2MB) | partial(SPLITK MB)
  char* ws = (char*)d_ws;
  ushort* Ah = (ushort*)ws;
  ushort* Al = (ushort*)(ws + (size_t)64 * LDA * 2);
  float* partial = (float*)(ws + (size_t)2 * 64 * LDA * 2);
  int SPLITK = 8;    // grid (32,8) = 256 blocks = exactly 1 resident block/CU
  while (SPLITK > 4 &&
         ws_size < (size_t)4 * 1024 * 1024 + (size_t)SPLITK * 1024 * 1024)
    SPLITK >>= 1;

  const int smem = 131072;   // 128KB dynamic LDS (> 64KB default: opt in)
  hipFuncSetAttribute((const void*)dag_gemm_phaseA<8>,
                      hipFuncAttributeMaxDynamicSharedMemorySize, smem);
  hipFuncSetAttribute((const void*)dag_gemm_phaseA<16>,
                      hipFuncAttributeMaxDynamicSharedMemorySize, smem);
  hipFuncSetAttribute((const void*)dag_gemm_phaseA<32>,
                      hipFuncAttributeMaxDynamicSharedMemorySize, smem);

  dag_splitx<<<256, 256, 0, stream>>>(x, Ah, Al);

  for (int k = 0; k < 4; ++k) {
    dim3 grid(32, SPLITK);
    const ushort* Ahp = Ah + Ls[k].incol;
    const ushort* Alp = Al + Ls[k].incol;
    int nsuper = (Ls[k].K / SPLITK) / 64;
    switch (nsuper) {
      case 8:
        dag_gemm_phaseA<8><<<grid, 512, smem, stream>>>(
            Ahp, Alp, Ls[k].W, Ls[k].M, partial, Ls[k].K);
        break;
      case 16:
        dag_gemm_phaseA<16><<<grid, 512, smem, stream>>>(
            Ahp, Alp, Ls[k].W, Ls[k].M, partial, Ls[k].K);
        break;
      default:
        dag_gemm_phaseA<32><<<grid, 512, smem, stream>>>(
            Ahp, Alp, Ls[k].W, Ls[k].M, partial, Ls[k].K);
        break;
    }
    bool last = (k == 3);
    dag_phaseB<<<512, 256, 0, stream>>>(
        partial, SPLITK, Ls[k].b,
        last ? (ushort*)nullptr : Ah + Ls[k].outcol,
        last ? (ushort*)nullptr : Al + Ls[k].outcol,
        last ? out : (float*)nullptr);
  }
}

// Round 17
// 248.293 us; speedup vs baseline: 1.8544x; 1.2286x over previous
//
#include <hip/hip_runtime.h>
#include <hip/hip_bf16.h>
#include <stdint.h>

// ---------------------------------------------------------------------------
// EfficientDAGNN: y_k = relu(concat(prev) @ (W_k*M_k)^T + b_k), 4 layers.
// FINAL (= R13, 257.7us best): global_load_lds staging w/ pre-swizzled
// source, double-buffered per-wave-private LDS, counted vmcnt, SPLITK=8
// (grid (32,8) = 256 blocks = 1 resident block/CU @ 128KB LDS).
// Failed directions (all regressed, reverted): cooperative mega-kernel
// (R2 +455us), 1-wave blocks (R4 spill), SPLITK=32 (R5 +72), 16n tile
// (R6/R16 +47..+90), fused epilogue (R7/R15 codegen collapse), 4-stage
// pipeline (R14 +7). Structure converged: phaseA is BW-queue-limited at
// ~80-85% of the fill-measured HBM ceiling; traffic floor is input-bound
// (W+M = 940MB read every call; mask-mul cannot be cached).
// Split-bf16 (hi+lo) 3-term MFMA, fp32 split-K partials, phaseB reduce.
// Activation plane: [64][16384] bf16 hi+lo, cols: [x | y1 | y2 | y3].
// ---------------------------------------------------------------------------

typedef __attribute__((ext_vector_type(8))) short  s8v;    // 8 bf16 (MFMA frag)
typedef __attribute__((ext_vector_type(4))) float  f4v;
typedef __attribute__((ext_vector_type(2))) float  f2v;
typedef __attribute__((ext_vector_type(4))) unsigned short us4v;
typedef __attribute__((ext_vector_type(2))) unsigned short us2v;

#define LDA 16384              // activation plane leading dim (bf16 elems)
#define MFMA16 __builtin_amdgcn_mfma_f32_16x16x32_bf16

typedef __attribute__((address_space(3))) void       lds_void;
typedef const __attribute__((address_space(1))) void g_void;

// fp32 -> bf16 RTNE (no NaNs in this problem)
__device__ __forceinline__ short f2bf(float f) {
  unsigned int u = __builtin_bit_cast(unsigned int, f);
  u += 0x7fffu + ((u >> 16) & 1u);
  return (short)(u >> 16);
}
__device__ __forceinline__ float bf2f(short s) {
  unsigned int u = ((unsigned int)(unsigned short)s) << 16;
  return __builtin_bit_cast(float, u);
}

// ---------------------------------------------------------------------------
// splitx: x (fp32 [64][4096]) -> xh/xl bf16 into cols [0,4096) of the plane
// ---------------------------------------------------------------------------
__global__ void dag_splitx(const float* __restrict__ x,
                           ushort* __restrict__ xh, ushort* __restrict__ xl) {
  int idx = blockIdx.x * blockDim.x + threadIdx.x;   // 65536 float4 units
  int m = idx >> 10;
  int n = (idx & 1023) << 2;
  f4v v = *(const f4v*)(x + (size_t)m * 4096 + n);
  us4v h, l;
#pragma unroll
  for (int j = 0; j < 4; ++j) {
    short hh = f2bf(v[j]);
    h[j] = (unsigned short)hh;
    l[j] = (unsigned short)f2bf(v[j] - bf2f(hh));
  }
  *(us4v*)(xh + (size_t)m * LDA + n) = h;
  *(us4v*)(xl + (size_t)m * LDA + n) = l;
}

// ---------------------------------------------------------------------------
// Phase A: partial[split][64][4096] = A[64][klen] @ (W*M)^T[klen][4096]
// Wave tile 64m x 32n. Per super-iter: 16 global_load_lds (8 W + 8 M, 1KB
// each, pre-swizzled source) DMA stage s+1 into the wave's spare LDS buffer
// while 2 MFMA k-steps consume stage s. Per-wave-private LDS: no barriers.
// grid = (32, SPLITK), block = 256 (4 waves), dynamic LDS 128KB.
// ---------------------------------------------------------------------------
struct RA { s8v ah0, ah1, ah2, ah3, al0, al1, al2, al3; };

template <int NSUPER>
__global__ __launch_bounds__(256, 1) void dag_gemm_phaseA(
    const ushort* __restrict__ Ah,   // already offset to layer's col start
    const ushort* __restrict__ Al,
    const float*  __restrict__ W,    // [4096][K] row-major
    const float*  __restrict__ Mm,   // [4096][K]
    float*        __restrict__ partial,  // [SPLITK][64][4096]
    int K) {
  extern __shared__ float smem[];    // 128KB: 4 waves x 2 stages x (W|M 8KB)
  const int tid  = threadIdx.x;
  const int wave = tid >> 6, lane = tid & 63;
  const int l15  = lane & 15, blk = lane >> 4;
  const int n0   = blockIdx.x * 128 + wave * 32;   // wave's output-col base
  const int klen = NSUPER * 64;
  const int kbeg = blockIdx.y * klen;

  float* base = smem + wave * 8192;  // 32KB per wave
  float* WL0 = base;                 // stage0 W [32][64]
  float* ML0 = base + 2048;          // stage0 M
  float* WL1 = base + 4096;          // stage1 W
  float* ML1 = base + 6144;          // stage1 M

  const int srow = lane >> 4;        // 0..3: row within 4-row group
  const int sc   = lane & 15;        // 16B chunk index within 256B row

  // A: lane reads row (mt*16+l15), 8 consecutive k (16B of bf16)
  const ushort* ap  = Ah + (size_t)l15 * LDA + kbeg + blk * 8;
  const ushort* alp = Al + (size_t)l15 * LDA + kbeg + blk * 8;

  f4v acc[4][2];
#pragma unroll
  for (int i = 0; i < 4; ++i) {
    acc[i][0] = (f4v){0.f, 0.f, 0.f, 0.f};
    acc[i][1] = (f4v){0.f, 0.f, 0.f, 0.f};
  }
  RA a0, a1;

  // DMA stage s into (WB, MB). Source pre-swizzled: lane (srow,sc) of instr
  // j loads global chunk sc ^ (row&15) of row 4j+srow; linear LDS dest
  // (base + lane*16B) then holds LDS[row][p] = global chunk p ^ (row&15).
  auto GLDS = [&](int s, float* WB, float* MB) {
#pragma unroll
    for (int j = 0; j < 8; ++j) {
      int row4 = 4 * j + srow;
      int gc   = sc ^ (row4 & 15);
      const float* ws = W  + (size_t)(n0 + row4) * K + kbeg + s * 64 + gc * 4;
      const float* ms = Mm + (size_t)(n0 + row4) * K + kbeg + s * 64 + gc * 4;
      __builtin_amdgcn_global_load_lds((g_void*)ws, (lds_void*)(WB + j * 256),
                                       16, 0, 0);
      __builtin_amdgcn_global_load_lds((g_void*)ms, (lds_void*)(MB + j * 256),
                                       16, 0, 0);
    }
  };
  auto LOADA = [&](RA& r, int ko) {
    r.ah0 = *(const s8v*)(ap  + ko);
    r.ah1 = *(const s8v*)(ap  + (size_t)16 * LDA + ko);
    r.ah2 = *(const s8v*)(ap  + (size_t)32 * LDA + ko);
    r.ah3 = *(const s8v*)(ap  + (size_t)48 * LDA + ko);
    r.al0 = *(const s8v*)(alp + ko);
    r.al1 = *(const s8v*)(alp + (size_t)16 * LDA + ko);
    r.al2 = *(const s8v*)(alp + (size_t)32 * LDA + ko);
    r.al3 = *(const s8v*)(alp + (size_t)48 * LDA + ko);
  };

  // One 32-k MFMA step: read swizzled W/M fragments from LDS, repack, 24 MFMA.
  auto KSTEP = [&](int kstep, RA& ra, float* WL, float* ML) {
    const int cc = kstep * 8 + blk * 2;
    const int c0 = cc ^ l15, c1 = (cc + 1) ^ l15;   // (row&15)==l15 both rows
    const float* wr0 = WL + l15 * 64;
    const float* wr1 = WL + (l15 + 16) * 64;
    const float* mr0 = ML + l15 * 64;
    const float* mr1 = ML + (l15 + 16) * 64;
    f4v w0a = *(const f4v*)(wr0 + c0 * 4), w0b = *(const f4v*)(wr0 + c1 * 4);
    f4v w1a = *(const f4v*)(wr1 + c0 * 4), w1b = *(const f4v*)(wr1 + c1 * 4);
    f4v m0a = *(const f4v*)(mr0 + c0 * 4), m0b = *(const f4v*)(mr0 + c1 * 4);
    f4v m1a = *(const f4v*)(mr1 + c0 * 4), m1b = *(const f4v*)(mr1 + c1 * 4);

    s8v wh0, wl0, wh1, wl1;
#pragma unroll
    for (int j = 0; j < 4; ++j) {
      { float ww = w0a[j] * m0a[j]; short h = f2bf(ww);
        wh0[j]     = h; wl0[j]     = f2bf(ww - bf2f(h)); }
      { float ww = w0b[j] * m0b[j]; short h = f2bf(ww);
        wh0[j + 4] = h; wl0[j + 4] = f2bf(ww - bf2f(h)); }
      { float ww = w1a[j] * m1a[j]; short h = f2bf(ww);
        wh1[j]     = h; wl1[j]     = f2bf(ww - bf2f(h)); }
      { float ww = w1b[j] * m1b[j]; short h = f2bf(ww);
        wh1[j + 4] = h; wl1[j + 4] = f2bf(ww - bf2f(h)); }
    }
    // 3-term split product: ah*wh + al*wh + ah*wl  (al*wl ~ 2^-18, dropped)
    acc[0][0] = MFMA16(ra.ah0, wh0, acc[0][0], 0, 0, 0);
    acc[0][0] = MFMA16(ra.al0, wh0, acc[0][0], 0, 0, 0);
    acc[0][0] = MFMA16(ra.ah0, wl0, acc[0][0], 0, 0, 0);
    acc[1][0] = MFMA16(ra.ah1, wh0, acc[1][0], 0, 0, 0);
    acc[1][0] = MFMA16(ra.al1, wh0, acc[1][0], 0, 0, 0);
    acc[1][0] = MFMA16(ra.ah1, wl0, acc[1][0], 0, 0, 0);
    acc[2][0] = MFMA16(ra.ah2, wh0, acc[2][0], 0, 0, 0);
    acc[2][0] = MFMA16(ra.al2, wh0, acc[2][0], 0, 0, 0);
    acc[2][0] = MFMA16(ra.ah2, wl0, acc[2][0], 0, 0, 0);
    acc[3][0] = MFMA16(ra.ah3, wh0, acc[3][0], 0, 0, 0);
    acc[3][0] = MFMA16(ra.al3, wh0, acc[3][0], 0, 0, 0);
    acc[3][0] = MFMA16(ra.ah3, wl0, acc[3][0], 0, 0, 0);
    acc[0][1] = MFMA16(ra.ah0, wh1, acc[0][1], 0, 0, 0);
    acc[0][1] = MFMA16(ra.al0, wh1, acc[0][1], 0, 0, 0);
    acc[0][1] = MFMA16(ra.ah0, wl1, acc[0][1], 0, 0, 0);
    acc[1][1] = MFMA16(ra.ah1, wh1, acc[1][1], 0, 0, 0);
    acc[1][1] = MFMA16(ra.al1, wh1, acc[1][1], 0, 0, 0);
    acc[1][1] = MFMA16(ra.ah1, wl1, acc[1][1], 0, 0, 0);
    acc[2][1] = MFMA16(ra.ah2, wh1, acc[2][1], 0, 0, 0);
    acc[2][1] = MFMA16(ra.al2, wh1, acc[2][1], 0, 0, 0);
    acc[2][1] = MFMA16(ra.ah2, wl1, acc[2][1], 0, 0, 0);
    acc[3][1] = MFMA16(ra.ah3, wh1, acc[3][1], 0, 0, 0);
    acc[3][1] = MFMA16(ra.al3, wh1, acc[3][1], 0, 0, 0);
    acc[3][1] = MFMA16(ra.ah3, wl1, acc[3][1], 0, 0, 0);
  };

  // prologue: DMA stage 0; A fragments for iter 0; drain the 16 DMA loads
  // (vmcnt(16) leaves the 16 A-loads in flight).
  GLDS(0, WL0, ML0);
  LOADA(a0, 0);
  LOADA(a1, 32);
  asm volatile("s_waitcnt vmcnt(16)" ::: "memory");
  __builtin_amdgcn_sched_barrier(0);

#pragma unroll
  for (int s = 0; s < NSUPER; ++s) {
    float* curW = (s & 1) ? WL1 : WL0;
    float* curM = (s & 1) ? ML1 : ML0;
    float* nxtW = (s & 1) ? WL0 : WL1;
    float* nxtM = (s & 1) ? ML0 : ML1;
    if (s + 1 < NSUPER) GLDS(s + 1, nxtW, nxtM);   // DMA next stage early
    KSTEP(0, a0, curW, curM);
    if (s + 1 < NSUPER) LOADA(a0, (s + 1) * 64);
    KSTEP(1, a1, curW, curM);
    if (s + 1 < NSUPER) LOADA(a1, (s + 1) * 64 + 32);
    if (s + 1 < NSUPER) {
      // drain this iter's 16 DMA loads; keep the 16 fresh A-loads in flight
      asm volatile("s_waitcnt vmcnt(16)" ::: "memory");
      __builtin_amdgcn_sched_barrier(0);
    }
  }

  // write fp32 partials: C row m = mt*16 + blk*4 + r, col n = n0 + nt*16 + l15
  float* pout = partial + (size_t)blockIdx.y * (64 * 4096);
#pragma unroll
  for (int mt = 0; mt < 4; ++mt)
#pragma unroll
    for (int nt = 0; nt < 2; ++nt) {
      int n = n0 + nt * 16 + l15;
#pragma unroll
      for (int rr = 0; rr < 4; ++rr) {
        int m = mt * 16 + blk * 4 + rr;
        pout[(size_t)m * 4096 + n] = acc[mt][nt][rr];
      }
    }
}

// ---------------------------------------------------------------------------
// Phase B: reduce split-K partials + bias + relu; re-split to bf16 hi/lo
// (next layer's input); layer 4 writes fp32 d_out instead.
// ---------------------------------------------------------------------------
__global__ void dag_phaseB(const float* __restrict__ partial, int splitk,
                           const float* __restrict__ bias,
                           ushort* __restrict__ yh, ushort* __restrict__ yl,
                           float* __restrict__ yf) {
  int idx = blockIdx.x * blockDim.x + threadIdx.x;   // 131072 f2v units
  int m = idx >> 11;
  int n = (idx & 2047) << 1;
  const float* p = partial + (size_t)m * 4096 + n;
  float s0 = 0.f, s1 = 0.f;
#pragma unroll 4
  for (int sp = 0; sp < splitk; ++sp) {
    f2v v = *(const f2v*)(p + (size_t)sp * (64 * 4096));
    s0 += v[0]; s1 += v[1];
  }
  const f2v bv = *(const f2v*)(bias + n);
  s0 = fmaxf(s0 + bv[0], 0.f);
  s1 = fmaxf(s1 + bv[1], 0.f);
  if (yf) {
    *(f2v*)(yf + (size_t)m * 4096 + n) = (f2v){s0, s1};
  } else {
    us2v h, l;
    short h0 = f2bf(s0); h[0] = (unsigned short)h0;
    l[0] = (unsigned short)f2bf(s0 - bf2f(h0));
    short h1 = f2bf(s1); h[1] = (unsigned short)h1;
    l[1] = (unsigned short)f2bf(s1 - bf2f(h1));
    *(us2v*)(yh + (size_t)m * LDA + n) = h;
    *(us2v*)(yl + (size_t)m * LDA + n) = l;
  }
}

// ---------------------------------------------------------------------------
extern "C" void kernel_launch(void* const* d_in, const int* in_sizes, int n_in,
                              void* d_out, int out_size, void* d_ws, size_t ws_size,
                              hipStream_t stream) {
  (void)in_sizes; (void)n_in; (void)out_size;
  const float* x = (const float*)d_in[0];
  struct L { const float *W, *b, *M; int K, incol, outcol; };
  L Ls[4] = {
      {(const float*)d_in[1],  (const float*)d_in[2],  (const float*)d_in[3],  4096, 0,    4096},
      {(const float*)d_in[4],  (const float*)d_in[5],  (const float*)d_in[6],  8192, 0,    8192},
      {(const float*)d_in[7],  (const float*)d_in[8],  (const float*)d_in[9],  8192, 4096, 12288},
      {(const float*)d_in[10], (const float*)d_in[11], (const float*)d_in[12], 8192, 8192, 16384},
  };
  float* out = (float*)d_out;

  // workspace: Ah(2MB) | Al(2MB) | partial(SPLITK MB)
  char* ws = (char*)d_ws;
  ushort* Ah = (ushort*)ws;
  ushort* Al = (ushort*)(ws + (size_t)64 * LDA * 2);
  float* partial = (float*)(ws + (size_t)2 * 64 * LDA * 2);
  int SPLITK = 8;    // grid (32,8) = 256 blocks = exactly 1 resident block/CU
  while (SPLITK > 4 &&
         ws_size < (size_t)4 * 1024 * 1024 + (size_t)SPLITK * 1024 * 1024)
    SPLITK >>= 1;

  const int smem = 131072;   // 128KB dynamic LDS (> 64KB default: opt in)
  hipFuncSetAttribute((const void*)dag_gemm_phaseA<8>,
                      hipFuncAttributeMaxDynamicSharedMemorySize, smem);
  hipFuncSetAttribute((const void*)dag_gemm_phaseA<16>,
                      hipFuncAttributeMaxDynamicSharedMemorySize, smem);
  hipFuncSetAttribute((const void*)dag_gemm_phaseA<32>,
                      hipFuncAttributeMaxDynamicSharedMemorySize, smem);

  dag_splitx<<<256, 256, 0, stream>>>(x, Ah, Al);

  for (int k = 0; k < 4; ++k) {
    dim3 grid(32, SPLITK);
    const ushort* Ahp = Ah + Ls[k].incol;
    const ushort* Alp = Al + Ls[k].incol;
    int nsuper = (Ls[k].K / SPLITK) / 64;
    switch (nsuper) {
      case 8:
        dag_gemm_phaseA<8><<<grid, 256, smem, stream>>>(
            Ahp, Alp, Ls[k].W, Ls[k].M, partial, Ls[k].K);
        break;
      case 16:
        dag_gemm_phaseA<16><<<grid, 256, smem, stream>>>(
            Ahp, Alp, Ls[k].W, Ls[k].M, partial, Ls[k].K);
        break;
      default:
        dag_gemm_phaseA<32><<<grid, 256, smem, stream>>>(
            Ahp, Alp, Ls[k].W, Ls[k].M, partial, Ls[k].K);
        break;
    }
    bool last = (k == 3);
    dag_phaseB<<<512, 256, 0, stream>>>(
        partial, SPLITK, Ls[k].b,
        last ? (ushort*)nullptr : Ah + Ls[k].outcol,
        last ? (ushort*)nullptr : Al + Ls[k].outcol,
        last ? out : (float*)nullptr);
  }
}